// Round 2
// baseline (1009.021 us; speedup 1.0000x reference)
//
#include <hip/hip_runtime.h>
#include <hip/hip_bf16.h>

#define HH 96
#define WW 160
#define BATCH 8
#define NPIX (BATCH*HH*WW)   // 122880
#define CIN 256
#define IMG (HH*WW)          // 15360
#define PW 162               // padded width
#define PH 98                // padded height
#define PR (PH*PW)           // 15876 padded rows per image
#define PTOT (BATCH*PR)      // 127008 padded rows total

typedef short bf16x8 __attribute__((ext_vector_type(8)));
typedef float f32x4 __attribute__((ext_vector_type(4)));

__device__ __forceinline__ unsigned short f2bf(float f) {
    unsigned int u = __float_as_uint(f);
    u = (u + 0x7fffu + ((u >> 16) & 1u)) >> 16;   // RNE
    return (unsigned short)u;
}

__device__ __forceinline__ void gload16(const void* g, void* l) {
    __builtin_amdgcn_global_load_lds(
        (const __attribute__((address_space(1))) void*)g,
        (__attribute__((address_space(3))) void*)l,
        16, 0, 0);
}

// ---------------- prep: BN fold ----------------
// scale1/bias1 are 384-entry combined arrays: [0,256) = conv1 BN fold, bias1[256..384) = ub1.
__global__ __launch_bounds__(256) void prep_scalars(
    const float* __restrict__ b1, const float* __restrict__ g1, const float* __restrict__ be1,
    const float* __restrict__ m1, const float* __restrict__ v1,
    const float* __restrict__ b2, const float* __restrict__ g2, const float* __restrict__ be2,
    const float* __restrict__ m2, const float* __restrict__ v2,
    const float* __restrict__ ub1,
    float* __restrict__ scale1, float* __restrict__ bias1,
    float* __restrict__ scale2, float* __restrict__ bias2)
{
    int t = threadIdx.x;
    float s1 = g1[t] * rsqrtf(v1[t] + 1e-5f);
    scale1[t] = s1;
    bias1[t]  = (b1[t] - m1[t]) * s1 + be1[t];
    float s2 = g2[t] * rsqrtf(v2[t] + 1e-5f);
    scale2[t] = s2;
    bias2[t]  = (b2[t] - m2[t]) * s2 + be2[t];
    if (t < 128) { scale1[256 + t] = 1.0f; bias1[256 + t] = ub1[t]; }
}

// ---------------- prep: pack weights OIHW f32 -> [cout][pos][cin] bf16 ----------------
__global__ __launch_bounds__(256) void prep_weights(
    const float* __restrict__ w1, const float* __restrict__ w2, const float* __restrict__ uw1,
    unsigned short* __restrict__ w1T, unsigned short* __restrict__ w2T, unsigned short* __restrict__ uw1T)
{
    const int S = 256 * 2304;       // 589824
    int i = blockIdx.x * 256 + threadIdx.x;
    if (i < S) {
        int co = i / 2304, r = i % 2304, pos = r >> 8, ci = r & 255;
        w1T[i] = f2bf(w1[(co * 256 + ci) * 9 + pos]);
    } else if (i < 2 * S) {
        int j = i - S;
        int co = j / 2304, r = j % 2304, pos = r >> 8, ci = r & 255;
        w2T[j] = f2bf(w2[(co * 256 + ci) * 9 + pos]);
    } else {
        int j = i - 2 * S;          // < 128*2304
        int co = j / 2304, r = j % 2304, pos = r >> 8, ci = r & 255;
        uw1T[j] = f2bf(uw1[(co * 256 + ci) * 9 + pos]);
    }
}

// ---------------- zero the pad rows of both padded buffers ----------------
__global__ __launch_bounds__(128) void zero_pads(
    unsigned int* __restrict__ featP, unsigned int* __restrict__ h1P)
{
    int bid = blockIdx.x;                 // 2 * 8 * 516 = 8256
    unsigned int* buf = (bid < 4128) ? featP : h1P;
    int k = (bid < 4128) ? bid : (bid - 4128);
    int img = k / 516, i = k % 516;
    int py, px;
    if (i < PW)            { py = 0;      px = i; }
    else if (i < 2 * PW)   { py = PH - 1; px = i - PW; }
    else { int q = i - 2 * PW; py = 1 + (q >> 1); px = (q & 1) ? (PW - 1) : 0; }
    size_t row = (size_t)img * PR + (size_t)py * PW + px;
    buf[row * 128 + threadIdx.x] = 0;     // 512 B row of zeros
}

// ---------------- prep: NCHW f32 -> padded NHWC bf16 ----------------
__global__ __launch_bounds__(256) void pack_features(
    const float* __restrict__ f, unsigned short* __restrict__ ft)
{
    __shared__ float tile[32][33];
    int x0 = blockIdx.x * 32;       // W/32 = 5
    int c0 = blockIdx.y * 32;       // C/32 = 8
    int by = blockIdx.z;            // B*H = 768
    int b = by / HH, y = by % HH;
    int tx = threadIdx.x & 31, tg = threadIdx.x >> 5;   // tg 0..7
    const float* src = f + (((size_t)(b * CIN + c0) * HH + y) * WW) + x0;
    #pragma unroll
    for (int i = 0; i < 4; ++i) {
        int cl = tg + i * 8;
        tile[cl][tx] = src[(size_t)cl * HH * WW + tx];
    }
    __syncthreads();
    size_t rbase = (size_t)b * PR + (size_t)(y + 1) * PW + (x0 + 1);
    #pragma unroll
    for (int i = 0; i < 4; ++i) {
        int xl = tg + i * 8;
        ft[(rbase + xl) * 256 + c0 + tx] = f2bf(tile[tx][xl]);
    }
}

// ---------------- 3x3 conv, implicit GEMM: A (weights) direct global->VGPR, B in LDS ----------------
// LDS-port analysis (r1): both sync structures capped at MfmaUtil 42% with 0 bank conflicts;
// per-CU-iter LDS-unit occupancy (reads 192 b128 + gload_lds writes) ~2800 cyc > MFMA 1863 cyc
// -> LDS throughput-bound. Fix: A fragments are loaded straight from wT (L1/L2-hot, 1.2 MB)
// into registers (fragment layout: lane l&15 = m-row, l>>4 = k-oct, 16 B each; 64B-line
// coalesced across quads), register-double-buffered one iteration ahead. This removes half
// the ds_reads and 73% of LDS writes. B stays LDS-staged (5.2x reuse): triple-buffered,
// ONE raw s_barrier per iteration (stage(t+1) targets buf[(t+1)%3], never the live buffer).
// Counted vmcnt: after issuing B-stage(t+1) [2; wave3 3] + 12 A loads(t+1), wait
// vmcnt(14/15) -> all of iteration t's ops landed; compiler auto-waits cover A-frag uses.
// Full 24x unroll keeps every buffer index static (no scratch) and all offsets immediate.
// XCD swizzle unchanged: 120 spatial blocks = one image per XCD.
// Row-wrap: pixel j with x0+j>=WW lives at padded addr r0+j+2.
// B swizzle (conflict-free): lane l stages row l>>2, quarter (l&3)^((l>>3)&3).
// mode 0: linear bf16 out (conv2), My=2.
// mode 1: merged conv1 (padded bf16 out, m0<256) + fused uncertainty head (m0==256), My=3.
__global__ __launch_bounds__(256, 2) void conv3x3_mfma(
    const unsigned short* __restrict__ inP,
    const unsigned short* __restrict__ wT,
    const float* __restrict__ scale, const float* __restrict__ bias,
    unsigned short* __restrict__ outT,
    float* __restrict__ uout,
    const float* __restrict__ uw2, const float* __restrict__ ub2,
    int Cout, int mode, int My)
{
    __shared__ unsigned short Blds[3][144 * 32];   // 3 x 9216 B
    __shared__ float usum[2][128];

    const int t = threadIdx.x;
    const int wave = t >> 6;
    const int l = t & 63;

    const int lid = blockIdx.x;
    const int xcd = lid & 7;
    const int j = lid >> 3;
    const int n0 = (xcd * 120 + j / My) * 128;
    const int m0 = (j % My) * 128;
    const bool is_unc = (mode == 1) && (m0 == 256);

    const int b0 = n0 / IMG;
    const int rem0 = n0 % IMG;
    const int y0 = rem0 / WW;
    const int x0 = rem0 % WW;
    const int r0 = b0 * PR + (y0 + 1) * PW + (x0 + 1);   // padded row of first output pixel

    const int lrow = l >> 2;
    const int lkq = (l & 3) ^ ((l >> 3) & 3);

    const int wm = wave >> 1, wn = wave & 1;
    const int quad = l >> 4, lane16 = l & 15;

    // A direct-from-global per-lane base (bytes): m-row = m0+wm*64+lane16 (+mt*16), k-oct = quad.
    // frag(mt, pos, cc) at aB + mt*73728 + pos*512 + cc*64  (wave-uniform offsets -> saddr folds)
    const char* aB = (const char*)wT +
        ((size_t)(m0 + wm * 64 + lane16) * 2304 + (size_t)quad * 8) * 2;

    char* BldsB = (char*)Blds;

    // B fragment base tile-rows: pixel j -> r0 + j (+2 if wrapped); staging origin
    // rs = r0 + (dyi-1)*PW - 8; dx adds 0..2; base = j + wrap + 7
    int browbase[4];
    #pragma unroll
    for (int i = 0; i < 4; ++i) {
        int jj = wn * 64 + i * 16 + lane16;
        browbase[i] = jj + ((x0 + jj) >= WW ? 2 : 0) + 7;
    }

    f32x4 acc[4][4];
    #pragma unroll
    for (int mt = 0; mt < 4; ++mt)
        #pragma unroll
        for (int nt = 0; nt < 4; ++nt)
            acc[mt][nt] = (f32x4){0.f, 0.f, 0.f, 0.f};

    bf16x8 afb[2][12];   // A-frag register double buffer; ALL indices static after unroll

    // stage B rows [r0 + (dyi-1)*PW - 8, +144) of cc-chunk into buffer sel (2 or 3 gload_lds)
    auto STAGE_B = [&](int ccoff, int dyi, int sel) {
        const ptrdiff_t rs = (ptrdiff_t)r0 + (ptrdiff_t)(dyi - 1) * PW - 8;
        const unsigned short* bs = inP + (rs + lrow) * 256 + ccoff + lkq * 8
                                       + (size_t)wave * 8192;   // wave covers slots 2w,2w+1
        char* bd = BldsB + sel * 9216;
        gload16(bs, bd + wave * 2048);
        gload16(bs + 4096, bd + wave * 2048 + 1024);
        if (wave == 3) gload16(bs + 8192, bd + 8192);           // slot 8
    };

    // prologue: stage iteration 0 (cc=0, dyi=0) -> B buf 0, A regs afb[0]
    STAGE_B(0, 0, 0);
    #pragma unroll
    for (int f = 0; f < 12; ++f) {
        const int dx = f / 4, mt = f % 4;     // pos = dx
        afb[0][f] = *(const bf16x8*)(aB + mt * 73728 + dx * 512);
    }

    #pragma unroll
    for (int it = 0; it < 24; ++it) {
        const int cur = it % 3;        // B LDS buffer for compute(it)
        const int pcur = it & 1;       // A reg buffer for compute(it)
        if (it < 23) {
            const int itn = it + 1;
            const int ccn = itn / 3, dyin = itn % 3;
            STAGE_B(ccn * 32, dyin, itn % 3);
            #pragma unroll
            for (int f = 0; f < 12; ++f) {
                const int dx = f / 4, mt = f % 4;
                afb[pcur ^ 1][f] = *(const bf16x8*)(aB + mt * 73728
                                                    + (dyin * 3 + dx) * 512 + ccn * 64);
            }
            __builtin_amdgcn_sched_barrier(0);
            // newest 14 (wave3: 15) outstanding = iteration it+1's ops -> all of it's landed
            if (wave == 3) { asm volatile("s_waitcnt vmcnt(15)" ::: "memory"); }
            else           { asm volatile("s_waitcnt vmcnt(14)" ::: "memory"); }
        } else {
            asm volatile("s_waitcnt vmcnt(0)" ::: "memory");
        }
        __builtin_amdgcn_s_barrier();            // all waves' B(it) landed
        asm volatile("" ::: "memory");           // fence: no ds_read hoisted above barrier

        __builtin_amdgcn_s_setprio(1);
        const char* Bb = BldsB + cur * 9216;
        #pragma unroll
        for (int dx = 0; dx < 3; ++dx) {
            bf16x8 bfr[4];
            #pragma unroll
            for (int i = 0; i < 4; ++i) {
                int row = browbase[i] + dx;
                int ba = (row << 6) + ((quad ^ ((row >> 1) & 3)) << 4);
                bfr[i] = *(const bf16x8*)(Bb + ba);
            }
            #pragma unroll
            for (int mt = 0; mt < 4; ++mt)
                #pragma unroll
                for (int nt = 0; nt < 4; ++nt)
                    acc[mt][nt] = __builtin_amdgcn_mfma_f32_16x16x32_bf16(
                        afb[pcur][dx * 4 + mt], bfr[nt], acc[mt][nt], 0, 0, 0);
        }
        __builtin_amdgcn_s_setprio(0);
        // no second barrier: stage(it+1) writes buf[(it+1)%3], never the buffer any wave
        // between barrier(it) and barrier(it+1) is reading (buf[it%3]).
    }

    if (is_unc) {
        // fused uncertainty head: relu(acc+ub1) dot uw2 over all 128 channels -> softplus
        const float* ub = bias + 256;
        float s[4] = {0.f, 0.f, 0.f, 0.f};
        #pragma unroll
        for (int mt = 0; mt < 4; ++mt) {
            const int mg = wm * 64 + mt * 16 + quad * 4;
            const float4 bi = *(const float4*)&ub[mg];
            const float4 uw = *(const float4*)&uw2[mg];
            #pragma unroll
            for (int nt = 0; nt < 4; ++nt) {
                s[nt] += fmaxf(acc[mt][nt][0] + bi.x, 0.f) * uw.x
                       + fmaxf(acc[mt][nt][1] + bi.y, 0.f) * uw.y
                       + fmaxf(acc[mt][nt][2] + bi.z, 0.f) * uw.z
                       + fmaxf(acc[mt][nt][3] + bi.w, 0.f) * uw.w;
            }
        }
        #pragma unroll
        for (int nt = 0; nt < 4; ++nt) {
            s[nt] += __shfl_xor(s[nt], 16);
            s[nt] += __shfl_xor(s[nt], 32);
        }
        if (quad == 0) {
            #pragma unroll
            for (int nt = 0; nt < 4; ++nt)
                usum[wm][wn * 64 + nt * 16 + lane16] = s[nt];
        }
        __syncthreads();
        if (t < 128) {
            float x = usum[0][t] + usum[1][t] + ub2[0];
            uout[n0 + t] = fmaxf(x, 0.f) + log1pf(expf(-fabsf(x)));
        }
        return;
    }

    // conv outputs: y = relu(acc*scale + bias) -> bf16 (mode1: padded rows; mode0: linear)
    size_t obase[4];
    #pragma unroll
    for (int nt = 0; nt < 4; ++nt) {
        int n = n0 + wn * 64 + nt * 16 + lane16;
        if (mode == 1) {
            int b = n / IMG, rem = n % IMG, yy = rem / WW, xx = rem % WW;
            obase[nt] = ((size_t)(b * PH + yy + 1) * PW + (xx + 1)) * 256;
        } else {
            obase[nt] = (size_t)n * Cout;
        }
    }
    #pragma unroll
    for (int mt = 0; mt < 4; ++mt) {
        const int mg = m0 + wm * 64 + mt * 16 + quad * 4;
        const float4 sc = *(const float4*)&scale[mg];
        const float4 bi = *(const float4*)&bias[mg];
        #pragma unroll
        for (int nt = 0; nt < 4; ++nt) {
            ushort4 pk;
            pk.x = f2bf(fmaxf(acc[mt][nt][0] * sc.x + bi.x, 0.f));
            pk.y = f2bf(fmaxf(acc[mt][nt][1] * sc.y + bi.y, 0.f));
            pk.z = f2bf(fmaxf(acc[mt][nt][2] * sc.z + bi.z, 0.f));
            pk.w = f2bf(fmaxf(acc[mt][nt][3] * sc.w + bi.w, 0.f));
            *(ushort4*)&outT[obase[nt] + mg] = pk;
        }
    }
}

// ---------------- depth head: 1x1 conv over 256ch + sigmoid + depth transform ----------------
__global__ __launch_bounds__(256) void head_depth(
    const unsigned short* __restrict__ h2, const float* __restrict__ w3,
    const float* __restrict__ b3, float* __restrict__ out)
{
    __shared__ float ws[256];
    ws[threadIdx.x] = w3[threadIdx.x];
    __syncthreads();
    const int pix = blockIdx.x * 64 + (threadIdx.x >> 2);
    const int q = threadIdx.x & 3;
    const unsigned short* p = h2 + (size_t)pix * 256 + q * 64;
    float s = 0.f;
    #pragma unroll
    for (int i = 0; i < 64; i += 8) {
        uint4 v = *(const uint4*)(p + i);
        const float* wq = &ws[q * 64 + i];
        s += __uint_as_float(v.x << 16) * wq[0];
        s += __uint_as_float(v.x & 0xffff0000u) * wq[1];
        s += __uint_as_float(v.y << 16) * wq[2];
        s += __uint_as_float(v.y & 0xffff0000u) * wq[3];
        s += __uint_as_float(v.z << 16) * wq[4];
        s += __uint_as_float(v.z & 0xffff0000u) * wq[5];
        s += __uint_as_float(v.w << 16) * wq[6];
        s += __uint_as_float(v.w & 0xffff0000u) * wq[7];
    }
    s += __shfl_xor(s, 1);
    s += __shfl_xor(s, 2);
    if (q == 0) {
        float x = s + b3[0];
        float sig = 1.f / (1.f + expf(-x));
        out[pix] = 1.f / (0.01f + 9.99f * sig);
    }
}

// ---------------- per-box lower-median via 4-pass radix select on float bits ----------------
__global__ __launch_bounds__(256) void median_kernel(
    const float* __restrict__ depth, const int* __restrict__ bboxes, float* __restrict__ obj)
{
    const int bi = blockIdx.x;          // b*64 + box
    const int b = bi >> 6;
    const int* bb = bboxes + (size_t)bi * 4;
    int x1 = max(bb[0], 0), y1 = max(bb[1], 0);
    int x2 = min(bb[2], WW), y2 = min(bb[3], HH);
    int w = x2 - x1, h = y2 - y1;
    if (w <= 0 || h <= 0) {
        if (threadIdx.x == 0) obj[bi] = 0.f;
        return;
    }
    const int wh = w * h;
    int tgt = (wh - 1) >> 1;            // lower median index
    const float* dbase = depth + (size_t)b * HH * WW;

    __shared__ unsigned int hist[256];
    __shared__ unsigned int sel_prefix, sel_target;
    unsigned int prefix = 0;

    for (int pass = 0; pass < 4; ++pass) {
        const int shift = 24 - 8 * pass;
        hist[threadIdx.x] = 0;
        __syncthreads();
        const unsigned int mask_high = (pass == 0) ? 0u : (0xFFFFFFFFu << (shift + 8));
        for (int idx = threadIdx.x; idx < wh; idx += 256) {
            int yy = y1 + idx / w, xx = x1 + idx % w;
            unsigned int uu = __float_as_uint(dbase[yy * WW + xx]);
            if ((uu & mask_high) == (prefix & mask_high))
                atomicAdd(&hist[(uu >> shift) & 255], 1u);
        }
        __syncthreads();
        if (threadIdx.x == 0) {
            unsigned int cum = 0;
            for (int bin = 0; bin < 256; ++bin) {
                unsigned int c = hist[bin];
                if (cum + c > (unsigned int)tgt) {
                    sel_target = (unsigned int)tgt - cum;
                    sel_prefix = prefix | ((unsigned int)bin << shift);
                    break;
                }
                cum += c;
            }
        }
        __syncthreads();
        prefix = sel_prefix;
        tgt = (int)sel_target;
    }
    if (threadIdx.x == 0) obj[bi] = __uint_as_float(prefix);
}

extern "C" void kernel_launch(void* const* d_in, const int* in_sizes, int n_in,
                              void* d_out, int out_size, void* d_ws, size_t ws_size,
                              hipStream_t stream) {
    const float* features = (const float*)d_in[0];
    const int*   bboxes   = (const int*)d_in[1];
    const float* w1  = (const float*)d_in[2];
    const float* b1  = (const float*)d_in[3];
    const float* g1  = (const float*)d_in[4];
    const float* be1 = (const float*)d_in[5];
    const float* m1  = (const float*)d_in[6];
    const float* v1  = (const float*)d_in[7];
    const float* w2  = (const float*)d_in[8];
    const float* b2  = (const float*)d_in[9];
    const float* g2  = (const float*)d_in[10];
    const float* be2 = (const float*)d_in[11];
    const float* m2  = (const float*)d_in[12];
    const float* v2  = (const float*)d_in[13];
    const float* w3  = (const float*)d_in[14];
    const float* b3  = (const float*)d_in[15];
    const float* uw1 = (const float*)d_in[16];
    const float* ub1 = (const float*)d_in[17];
    const float* uw2 = (const float*)d_in[18];
    const float* ub2 = (const float*)d_in[19];
    float* out = (float*)d_out;

    char* ws = (char*)d_ws;
    // layout (bytes). Padded buffers have 8 KB read-slack gaps on both sides.
    unsigned short* featP = (unsigned short*)(ws + 8192);        // 65,028,096 -> end 65,036,288
    unsigned short* h1P   = (unsigned short*)(ws + 65044480);    // end 130,072,576
    unsigned short* h2    = (unsigned short*)(ws + 8192);        // alias featP (dead after conv1 pass)
    unsigned short* w1T   = (unsigned short*)(ws + 130080768);   // 256 rows, 1,179,648 B
    unsigned short* uw1T  = w1T + 256 * 2304;                    // 128 rows right after -> combined 384
    unsigned short* w2T   = uw1T + 128 * 2304;                   // 1,179,648 B
    float* scale1 = (float*)(w2T + 589824);                      // 384
    float* bias1  = scale1 + 384;                                // 384 (256 BN-fold + 128 ub1)
    float* scale2 = bias1 + 384;                                 // 256
    float* bias2  = scale2 + 256;                                // 256

    prep_scalars<<<1, 256, 0, stream>>>(b1, g1, be1, m1, v1, b2, g2, be2, m2, v2, ub1,
                                        scale1, bias1, scale2, bias2);
    prep_weights<<<5760, 256, 0, stream>>>(w1, w2, uw1, w1T, w2T, uw1T);
    zero_pads<<<8256, 128, 0, stream>>>((unsigned int*)featP, (unsigned int*)h1P);
    pack_features<<<dim3(WW / 32, CIN / 32, BATCH * HH), 256, 0, stream>>>(features, featP);

    // merged conv1 (BN+ReLU, padded out) + fused uncertainty head; My=3, 2880 blocks
    conv3x3_mfma<<<2880, 256, 0, stream>>>(
        featP, w1T, scale1, bias1, h1P, out + NPIX, uw2, ub2, 256, 1, 3);
    // conv2: h1P -> h2 (linear out; featP dead, h2 aliases it); My=2, 1920 blocks
    conv3x3_mfma<<<1920, 256, 0, stream>>>(
        h1P, w2T, scale2, bias2, h2, nullptr, nullptr, nullptr, 256, 0, 2);

    head_depth<<<NPIX / 64, 256, 0, stream>>>(h2, w3, b3, out);
    median_kernel<<<BATCH * 64, 256, 0, stream>>>(out, bboxes, out + 2 * NPIX);
}

// Round 3
// 649.723 us; speedup vs baseline: 1.5530x; 1.5530x over previous
//
#include <hip/hip_runtime.h>
#include <hip/hip_bf16.h>

#define HH 96
#define WW 160
#define BATCH 8
#define NPIX (BATCH*HH*WW)   // 122880
#define CIN 256
#define IMG (HH*WW)          // 15360
#define PW 162               // padded width
#define PH 98                // padded height
#define PR (PH*PW)           // 15876 padded rows per image
#define PTOT (BATCH*PR)      // 127008 padded rows total

typedef short bf16x8 __attribute__((ext_vector_type(8)));
typedef float f32x4 __attribute__((ext_vector_type(4)));

__device__ __forceinline__ unsigned short f2bf(float f) {
    unsigned int u = __float_as_uint(f);
    u = (u + 0x7fffu + ((u >> 16) & 1u)) >> 16;   // RNE
    return (unsigned short)u;
}

__device__ __forceinline__ void gload16(const void* g, void* l) {
    __builtin_amdgcn_global_load_lds(
        (const __attribute__((address_space(1))) void*)g,
        (__attribute__((address_space(3))) void*)l,
        16, 0, 0);
}

// ---------------- prep: BN fold ----------------
// scale1/bias1 are 384-entry combined arrays: [0,256) = conv1 BN fold, bias1[256..384) = ub1.
__global__ __launch_bounds__(256) void prep_scalars(
    const float* __restrict__ b1, const float* __restrict__ g1, const float* __restrict__ be1,
    const float* __restrict__ m1, const float* __restrict__ v1,
    const float* __restrict__ b2, const float* __restrict__ g2, const float* __restrict__ be2,
    const float* __restrict__ m2, const float* __restrict__ v2,
    const float* __restrict__ ub1,
    float* __restrict__ scale1, float* __restrict__ bias1,
    float* __restrict__ scale2, float* __restrict__ bias2)
{
    int t = threadIdx.x;
    float s1 = g1[t] * rsqrtf(v1[t] + 1e-5f);
    scale1[t] = s1;
    bias1[t]  = (b1[t] - m1[t]) * s1 + be1[t];
    float s2 = g2[t] * rsqrtf(v2[t] + 1e-5f);
    scale2[t] = s2;
    bias2[t]  = (b2[t] - m2[t]) * s2 + be2[t];
    if (t < 128) { scale1[256 + t] = 1.0f; bias1[256 + t] = ub1[t]; }
}

// ---------------- prep: pack weights OIHW f32 -> [cout][pos][cin] bf16 ----------------
__global__ __launch_bounds__(256) void prep_weights(
    const float* __restrict__ w1, const float* __restrict__ w2, const float* __restrict__ uw1,
    unsigned short* __restrict__ w1T, unsigned short* __restrict__ w2T, unsigned short* __restrict__ uw1T)
{
    const int S = 256 * 2304;       // 589824
    int i = blockIdx.x * 256 + threadIdx.x;
    if (i < S) {
        int co = i / 2304, r = i % 2304, pos = r >> 8, ci = r & 255;
        w1T[i] = f2bf(w1[(co * 256 + ci) * 9 + pos]);
    } else if (i < 2 * S) {
        int j = i - S;
        int co = j / 2304, r = j % 2304, pos = r >> 8, ci = r & 255;
        w2T[j] = f2bf(w2[(co * 256 + ci) * 9 + pos]);
    } else {
        int j = i - 2 * S;          // < 128*2304
        int co = j / 2304, r = j % 2304, pos = r >> 8, ci = r & 255;
        uw1T[j] = f2bf(uw1[(co * 256 + ci) * 9 + pos]);
    }
}

// ---------------- zero the pad rows of both padded buffers ----------------
__global__ __launch_bounds__(128) void zero_pads(
    unsigned int* __restrict__ featP, unsigned int* __restrict__ h1P)
{
    int bid = blockIdx.x;                 // 2 * 8 * 516 = 8256
    unsigned int* buf = (bid < 4128) ? featP : h1P;
    int k = (bid < 4128) ? bid : (bid - 4128);
    int img = k / 516, i = k % 516;
    int py, px;
    if (i < PW)            { py = 0;      px = i; }
    else if (i < 2 * PW)   { py = PH - 1; px = i - PW; }
    else { int q = i - 2 * PW; py = 1 + (q >> 1); px = (q & 1) ? (PW - 1) : 0; }
    size_t row = (size_t)img * PR + (size_t)py * PW + px;
    buf[row * 128 + threadIdx.x] = 0;     // 512 B row of zeros
}

// ---------------- prep: NCHW f32 -> padded NHWC bf16 ----------------
__global__ __launch_bounds__(256) void pack_features(
    const float* __restrict__ f, unsigned short* __restrict__ ft)
{
    __shared__ float tile[32][33];
    int x0 = blockIdx.x * 32;       // W/32 = 5
    int c0 = blockIdx.y * 32;       // C/32 = 8
    int by = blockIdx.z;            // B*H = 768
    int b = by / HH, y = by % HH;
    int tx = threadIdx.x & 31, tg = threadIdx.x >> 5;   // tg 0..7
    const float* src = f + (((size_t)(b * CIN + c0) * HH + y) * WW) + x0;
    #pragma unroll
    for (int i = 0; i < 4; ++i) {
        int cl = tg + i * 8;
        tile[cl][tx] = src[(size_t)cl * HH * WW + tx];
    }
    __syncthreads();
    size_t rbase = (size_t)b * PR + (size_t)(y + 1) * PW + (x0 + 1);
    #pragma unroll
    for (int i = 0; i < 4; ++i) {
        int xl = tg + i * 8;
        ft[(rbase + xl) * 256 + c0 + tx] = f2bf(tile[tx][xl]);
    }
}

// ---------------- 3x3 conv, implicit GEMM, padded input, shared-dy B staging ----------------
// Occupancy analysis (r2 post-mortem): r0/r1 both idle ~46% of wall with no pipe >50% busy
// and 2 waves/SIMD (VGPR 112 + AGPR 64 = 176 > 170 = 512/3). The latency/serialization is
// filled by a THIRD co-resident block per CU at an independent loop phase (m114 overlap).
// -> single-buffer LDS (34.8 KB; x3 = 104 KB fits) + __launch_bounds__(256,3) to cap regs.
// XCD swizzle: l=(xcd,j); spatial s = xcd*120 + j/My, m-tile = j%My. 120 spatial
// blocks = exactly one image per XCD -> B dy-overlap + cross-m reuse hit that XCD's L2.
// K loop = 8 cc-chunks x 3 dy; 24 barrier pairs, 48 MFMA/wave/pair.
// Row-wrap: pixel j with x0+j>=WW lives at padded addr r0+j+(PW-WW)=r0+j+2.
// Swizzle (conflict-free): lane l stages row l>>2, quarter (l&3)^((l>>3)&3).
// mode 0: linear bf16 out (conv2), My=2.
// mode 1: merged conv1 (padded bf16 out, m0<256) + fused uncertainty head (m0==256), My=3.
__global__ __launch_bounds__(256, 3) void conv3x3_mfma(
    const unsigned short* __restrict__ inP,
    const unsigned short* __restrict__ wT,
    const float* __restrict__ scale, const float* __restrict__ bias,
    unsigned short* __restrict__ outT,
    float* __restrict__ uout,
    const float* __restrict__ uw2, const float* __restrict__ ub2,
    int Cout, int mode, int My)
{
    __shared__ unsigned short Alds[3 * 128 * 32];   // 24576 B, [pos][slot][...]
    __shared__ unsigned short Blds[144 * 32];       // 9216 B
    __shared__ float usum[2][128];

    const int t = threadIdx.x;
    const int wave = t >> 6;
    const int l = t & 63;

    const int lid = blockIdx.x;
    const int xcd = lid & 7;
    const int j = lid >> 3;
    const int n0 = (xcd * 120 + j / My) * 128;
    const int m0 = (j % My) * 128;
    const bool is_unc = (mode == 1) && (m0 == 256);

    const int b0 = n0 / IMG;
    const int rem0 = n0 % IMG;
    const int y0 = rem0 / WW;
    const int x0 = rem0 % WW;
    const int r0 = b0 * PR + (y0 + 1) * PW + (x0 + 1);   // padded row of first output pixel

    const int lrow = l >> 2;
    const int lkq = (l & 3) ^ ((l >> 3) & 3);

    // A staging per-lane source bases (two 16-row slots per wave)
    const unsigned short* asrc0 = wT + (size_t)(m0 + wave * 32 + lrow) * 9 * 256 + lkq * 8;
    const unsigned short* asrc1 = asrc0 + (size_t)16 * 9 * 256;

    char* AldsB = (char*)Alds;
    char* BldsB = (char*)Blds;
    char* aldst = AldsB + wave * 2048;   // + dx*8192 (+1024 for second slot)

    const int wm = wave >> 1, wn = wave & 1;
    const int quad = l >> 4, lane16 = l & 15;
    const int aoff = lane16 * 64 + ((quad ^ ((lane16 >> 1) & 3)) << 4);

    // B fragment base tile-rows: pixel j -> r0 + j (+2 if wrapped); staging origin
    // rs = r0 + (dyi-1)*PW - 8; dx adds 0..2; base = j + wrap + 7
    int browbase[4];
    #pragma unroll
    for (int i = 0; i < 4; ++i) {
        int jj = wn * 64 + i * 16 + lane16;
        browbase[i] = jj + ((x0 + jj) >= WW ? 2 : 0) + 7;
    }

    f32x4 acc[4][4];
    #pragma unroll
    for (int mt = 0; mt < 4; ++mt)
        #pragma unroll
        for (int nt = 0; nt < 4; ++nt)
            acc[mt][nt] = (f32x4){0.f, 0.f, 0.f, 0.f};

    for (int cc = 0; cc < 8; ++cc) {
        const int ccoff = cc * 32;
        for (int dyi = 0; dyi < 3; ++dyi) {
            __syncthreads();
            // ---- stage A: 3 pos-tiles (pos = dyi*3 + dx), 6 instr/wave
            const unsigned short* a0 = asrc0 + (dyi * 3) * 256 + ccoff;
            const unsigned short* a1 = asrc1 + (dyi * 3) * 256 + ccoff;
            #pragma unroll
            for (int dxp = 0; dxp < 3; ++dxp) {
                gload16(a0 + dxp * 256, aldst + dxp * 8192);
                gload16(a1 + dxp * 256, aldst + dxp * 8192 + 1024);
            }
            // ---- stage B: 144 padded rows [r0 + (dyi-1)*PW - 8, +144), 9 slots
            const ptrdiff_t rs = (ptrdiff_t)r0 + (ptrdiff_t)(dyi - 1) * PW - 8;
            const unsigned short* bs = inP + (rs + lrow) * 256 + ccoff + lkq * 8
                                           + (size_t)wave * 8192;   // wave covers slots 2w,2w+1
            gload16(bs, BldsB + wave * 2048);
            gload16(bs + 4096, BldsB + wave * 2048 + 1024);
            if (wave == 3) gload16(bs + 8192, BldsB + 8192);        // slot 8
            __syncthreads();
            // ---- compute: 3 dx shifts x 16 MFMA
            #pragma unroll
            for (int dx = 0; dx < 3; ++dx) {
                bf16x8 af[4], bfr[4];
                #pragma unroll
                for (int mt = 0; mt < 4; ++mt)
                    af[mt] = *(const bf16x8*)(AldsB + dx * 8192 + ((wm * 4 + mt) << 10) + aoff);
                #pragma unroll
                for (int i = 0; i < 4; ++i) {
                    int row = browbase[i] + dx;
                    int ba = (row << 6) + ((quad ^ ((row >> 1) & 3)) << 4);
                    bfr[i] = *(const bf16x8*)(BldsB + ba);
                }
                #pragma unroll
                for (int mt = 0; mt < 4; ++mt)
                    #pragma unroll
                    for (int nt = 0; nt < 4; ++nt)
                        acc[mt][nt] = __builtin_amdgcn_mfma_f32_16x16x32_bf16(
                            af[mt], bfr[nt], acc[mt][nt], 0, 0, 0);
            }
        }
    }

    if (is_unc) {
        // fused uncertainty head: relu(acc+ub1) dot uw2 over all 128 channels -> softplus
        const float* ub = bias + 256;
        float s[4] = {0.f, 0.f, 0.f, 0.f};
        #pragma unroll
        for (int mt = 0; mt < 4; ++mt) {
            const int mg = wm * 64 + mt * 16 + quad * 4;
            const float4 bi = *(const float4*)&ub[mg];
            const float4 uw = *(const float4*)&uw2[mg];
            #pragma unroll
            for (int nt = 0; nt < 4; ++nt) {
                s[nt] += fmaxf(acc[mt][nt][0] + bi.x, 0.f) * uw.x
                       + fmaxf(acc[mt][nt][1] + bi.y, 0.f) * uw.y
                       + fmaxf(acc[mt][nt][2] + bi.z, 0.f) * uw.z
                       + fmaxf(acc[mt][nt][3] + bi.w, 0.f) * uw.w;
            }
        }
        #pragma unroll
        for (int nt = 0; nt < 4; ++nt) {
            s[nt] += __shfl_xor(s[nt], 16);
            s[nt] += __shfl_xor(s[nt], 32);
        }
        if (quad == 0) {
            #pragma unroll
            for (int nt = 0; nt < 4; ++nt)
                usum[wm][wn * 64 + nt * 16 + lane16] = s[nt];
        }
        __syncthreads();
        if (t < 128) {
            float x = usum[0][t] + usum[1][t] + ub2[0];
            uout[n0 + t] = fmaxf(x, 0.f) + log1pf(expf(-fabsf(x)));
        }
        return;
    }

    // conv outputs: y = relu(acc*scale + bias) -> bf16 (mode1: padded rows; mode0: linear)
    size_t obase[4];
    #pragma unroll
    for (int nt = 0; nt < 4; ++nt) {
        int n = n0 + wn * 64 + nt * 16 + lane16;
        if (mode == 1) {
            int b = n / IMG, rem = n % IMG, yy = rem / WW, xx = rem % WW;
            obase[nt] = ((size_t)(b * PH + yy + 1) * PW + (xx + 1)) * 256;
        } else {
            obase[nt] = (size_t)n * Cout;
        }
    }
    #pragma unroll
    for (int mt = 0; mt < 4; ++mt) {
        const int mg = m0 + wm * 64 + mt * 16 + quad * 4;
        const float4 sc = *(const float4*)&scale[mg];
        const float4 bi = *(const float4*)&bias[mg];
        #pragma unroll
        for (int nt = 0; nt < 4; ++nt) {
            ushort4 pk;
            pk.x = f2bf(fmaxf(acc[mt][nt][0] * sc.x + bi.x, 0.f));
            pk.y = f2bf(fmaxf(acc[mt][nt][1] * sc.y + bi.y, 0.f));
            pk.z = f2bf(fmaxf(acc[mt][nt][2] * sc.z + bi.z, 0.f));
            pk.w = f2bf(fmaxf(acc[mt][nt][3] * sc.w + bi.w, 0.f));
            *(ushort4*)&outT[obase[nt] + mg] = pk;
        }
    }
}

// ---------------- depth head: 1x1 conv over 256ch + sigmoid + depth transform ----------------
__global__ __launch_bounds__(256) void head_depth(
    const unsigned short* __restrict__ h2, const float* __restrict__ w3,
    const float* __restrict__ b3, float* __restrict__ out)
{
    __shared__ float ws[256];
    ws[threadIdx.x] = w3[threadIdx.x];
    __syncthreads();
    const int pix = blockIdx.x * 64 + (threadIdx.x >> 2);
    const int q = threadIdx.x & 3;
    const unsigned short* p = h2 + (size_t)pix * 256 + q * 64;
    float s = 0.f;
    #pragma unroll
    for (int i = 0; i < 64; i += 8) {
        uint4 v = *(const uint4*)(p + i);
        const float* wq = &ws[q * 64 + i];
        s += __uint_as_float(v.x << 16) * wq[0];
        s += __uint_as_float(v.x & 0xffff0000u) * wq[1];
        s += __uint_as_float(v.y << 16) * wq[2];
        s += __uint_as_float(v.y & 0xffff0000u) * wq[3];
        s += __uint_as_float(v.z << 16) * wq[4];
        s += __uint_as_float(v.z & 0xffff0000u) * wq[5];
        s += __uint_as_float(v.w << 16) * wq[6];
        s += __uint_as_float(v.w & 0xffff0000u) * wq[7];
    }
    s += __shfl_xor(s, 1);
    s += __shfl_xor(s, 2);
    if (q == 0) {
        float x = s + b3[0];
        float sig = 1.f / (1.f + expf(-x));
        out[pix] = 1.f / (0.01f + 9.99f * sig);
    }
}

// ---------------- per-box lower-median via 4-pass radix select on float bits ----------------
__global__ __launch_bounds__(256) void median_kernel(
    const float* __restrict__ depth, const int* __restrict__ bboxes, float* __restrict__ obj)
{
    const int bi = blockIdx.x;          // b*64 + box
    const int b = bi >> 6;
    const int* bb = bboxes + (size_t)bi * 4;
    int x1 = max(bb[0], 0), y1 = max(bb[1], 0);
    int x2 = min(bb[2], WW), y2 = min(bb[3], HH);
    int w = x2 - x1, h = y2 - y1;
    if (w <= 0 || h <= 0) {
        if (threadIdx.x == 0) obj[bi] = 0.f;
        return;
    }
    const int wh = w * h;
    int tgt = (wh - 1) >> 1;            // lower median index
    const float* dbase = depth + (size_t)b * HH * WW;

    __shared__ unsigned int hist[256];
    __shared__ unsigned int sel_prefix, sel_target;
    unsigned int prefix = 0;

    for (int pass = 0; pass < 4; ++pass) {
        const int shift = 24 - 8 * pass;
        hist[threadIdx.x] = 0;
        __syncthreads();
        const unsigned int mask_high = (pass == 0) ? 0u : (0xFFFFFFFFu << (shift + 8));
        for (int idx = threadIdx.x; idx < wh; idx += 256) {
            int yy = y1 + idx / w, xx = x1 + idx % w;
            unsigned int uu = __float_as_uint(dbase[yy * WW + xx]);
            if ((uu & mask_high) == (prefix & mask_high))
                atomicAdd(&hist[(uu >> shift) & 255], 1u);
        }
        __syncthreads();
        if (threadIdx.x == 0) {
            unsigned int cum = 0;
            for (int bin = 0; bin < 256; ++bin) {
                unsigned int c = hist[bin];
                if (cum + c > (unsigned int)tgt) {
                    sel_target = (unsigned int)tgt - cum;
                    sel_prefix = prefix | ((unsigned int)bin << shift);
                    break;
                }
                cum += c;
            }
        }
        __syncthreads();
        prefix = sel_prefix;
        tgt = (int)sel_target;
    }
    if (threadIdx.x == 0) obj[bi] = __uint_as_float(prefix);
}

extern "C" void kernel_launch(void* const* d_in, const int* in_sizes, int n_in,
                              void* d_out, int out_size, void* d_ws, size_t ws_size,
                              hipStream_t stream) {
    const float* features = (const float*)d_in[0];
    const int*   bboxes   = (const int*)d_in[1];
    const float* w1  = (const float*)d_in[2];
    const float* b1  = (const float*)d_in[3];
    const float* g1  = (const float*)d_in[4];
    const float* be1 = (const float*)d_in[5];
    const float* m1  = (const float*)d_in[6];
    const float* v1  = (const float*)d_in[7];
    const float* w2  = (const float*)d_in[8];
    const float* b2  = (const float*)d_in[9];
    const float* g2  = (const float*)d_in[10];
    const float* be2 = (const float*)d_in[11];
    const float* m2  = (const float*)d_in[12];
    const float* v2  = (const float*)d_in[13];
    const float* w3  = (const float*)d_in[14];
    const float* b3  = (const float*)d_in[15];
    const float* uw1 = (const float*)d_in[16];
    const float* ub1 = (const float*)d_in[17];
    const float* uw2 = (const float*)d_in[18];
    const float* ub2 = (const float*)d_in[19];
    float* out = (float*)d_out;

    char* ws = (char*)d_ws;
    // layout (bytes). Padded buffers have 8 KB read-slack gaps on both sides.
    unsigned short* featP = (unsigned short*)(ws + 8192);        // 65,028,096 -> end 65,036,288
    unsigned short* h1P   = (unsigned short*)(ws + 65044480);    // end 130,072,576
    unsigned short* h2    = (unsigned short*)(ws + 8192);        // alias featP (dead after conv1 pass)
    unsigned short* w1T   = (unsigned short*)(ws + 130080768);   // 256 rows, 1,179,648 B
    unsigned short* uw1T  = w1T + 256 * 2304;                    // 128 rows right after -> combined 384
    unsigned short* w2T   = uw1T + 128 * 2304;                   // 1,179,648 B
    float* scale1 = (float*)(w2T + 589824);                      // 384
    float* bias1  = scale1 + 384;                                // 384 (256 BN-fold + 128 ub1)
    float* scale2 = bias1 + 384;                                 // 256
    float* bias2  = scale2 + 256;                                // 256

    prep_scalars<<<1, 256, 0, stream>>>(b1, g1, be1, m1, v1, b2, g2, be2, m2, v2, ub1,
                                        scale1, bias1, scale2, bias2);
    prep_weights<<<5760, 256, 0, stream>>>(w1, w2, uw1, w1T, w2T, uw1T);
    zero_pads<<<8256, 128, 0, stream>>>((unsigned int*)featP, (unsigned int*)h1P);
    pack_features<<<dim3(WW / 32, CIN / 32, BATCH * HH), 256, 0, stream>>>(features, featP);

    // merged conv1 (BN+ReLU, padded out) + fused uncertainty head; My=3, 2880 blocks
    conv3x3_mfma<<<2880, 256, 0, stream>>>(
        featP, w1T, scale1, bias1, h1P, out + NPIX, uw2, ub2, 256, 1, 3);
    // conv2: h1P -> h2 (linear out; featP dead, h2 aliases it); My=2, 1920 blocks
    conv3x3_mfma<<<1920, 256, 0, stream>>>(
        h1P, w2T, scale2, bias2, h2, nullptr, nullptr, nullptr, 256, 0, 2);

    head_depth<<<NPIX / 64, 256, 0, stream>>>(h2, w3, b3, out);
    median_kernel<<<BATCH * 64, 256, 0, stream>>>(out, bboxes, out + 2 * NPIX);
}

// Round 5
// 629.131 us; speedup vs baseline: 1.6038x; 1.0327x over previous
//
#include <hip/hip_runtime.h>
#include <hip/hip_bf16.h>

#define HH 96
#define WW 160
#define BATCH 8
#define NPIX (BATCH*HH*WW)   // 122880
#define CIN 256
#define IMG (HH*WW)          // 15360
#define PW 162               // padded width
#define PH 98                // padded height
#define PR (PH*PW)           // 15876 padded rows per image
#define PTOT (BATCH*PR)      // 127008 padded rows total

typedef short bf16x8 __attribute__((ext_vector_type(8)));
typedef float f32x4 __attribute__((ext_vector_type(4)));

__device__ __forceinline__ unsigned short f2bf(float f) {
    unsigned int u = __float_as_uint(f);
    u = (u + 0x7fffu + ((u >> 16) & 1u)) >> 16;   // RNE
    return (unsigned short)u;
}

__device__ __forceinline__ void gload16(const void* g, void* l) {
    __builtin_amdgcn_global_load_lds(
        (const __attribute__((address_space(1))) void*)g,
        (__attribute__((address_space(3))) void*)l,
        16, 0, 0);
}

// ---------------- prep: BN fold ----------------
// scale1/bias1 are 384-entry combined arrays: [0,256) = conv1 BN fold, bias1[256..384) = ub1.
__global__ __launch_bounds__(256) void prep_scalars(
    const float* __restrict__ b1, const float* __restrict__ g1, const float* __restrict__ be1,
    const float* __restrict__ m1, const float* __restrict__ v1,
    const float* __restrict__ b2, const float* __restrict__ g2, const float* __restrict__ be2,
    const float* __restrict__ m2, const float* __restrict__ v2,
    const float* __restrict__ ub1,
    float* __restrict__ scale1, float* __restrict__ bias1,
    float* __restrict__ scale2, float* __restrict__ bias2)
{
    int t = threadIdx.x;
    float s1 = g1[t] * rsqrtf(v1[t] + 1e-5f);
    scale1[t] = s1;
    bias1[t]  = (b1[t] - m1[t]) * s1 + be1[t];
    float s2 = g2[t] * rsqrtf(v2[t] + 1e-5f);
    scale2[t] = s2;
    bias2[t]  = (b2[t] - m2[t]) * s2 + be2[t];
    if (t < 128) { scale1[256 + t] = 1.0f; bias1[256 + t] = ub1[t]; }
}

// ---------------- prep: pack weights OIHW f32 -> [cout][pos][cin] bf16 ----------------
__global__ __launch_bounds__(256) void prep_weights(
    const float* __restrict__ w1, const float* __restrict__ w2, const float* __restrict__ uw1,
    unsigned short* __restrict__ w1T, unsigned short* __restrict__ w2T, unsigned short* __restrict__ uw1T)
{
    const int S = 256 * 2304;       // 589824
    int i = blockIdx.x * 256 + threadIdx.x;
    if (i < S) {
        int co = i / 2304, r = i % 2304, pos = r >> 8, ci = r & 255;
        w1T[i] = f2bf(w1[(co * 256 + ci) * 9 + pos]);
    } else if (i < 2 * S) {
        int j = i - S;
        int co = j / 2304, r = j % 2304, pos = r >> 8, ci = r & 255;
        w2T[j] = f2bf(w2[(co * 256 + ci) * 9 + pos]);
    } else {
        int j = i - 2 * S;          // < 128*2304
        int co = j / 2304, r = j % 2304, pos = r >> 8, ci = r & 255;
        uw1T[j] = f2bf(uw1[(co * 256 + ci) * 9 + pos]);
    }
}

// ---------------- zero pad rows of padded buffers + zero the depth-accumulator region ----------------
__global__ __launch_bounds__(128) void zero_pads(
    unsigned int* __restrict__ featP, unsigned int* __restrict__ h1P, float* __restrict__ outd)
{
    int bid = blockIdx.x;                 // 8256 pad blocks + 960 depth-zero blocks
    if (bid < 8256) {
        unsigned int* buf = (bid < 4128) ? featP : h1P;
        int k = (bid < 4128) ? bid : (bid - 4128);
        int img = k / 516, i = k % 516;
        int py, px;
        if (i < PW)            { py = 0;      px = i; }
        else if (i < 2 * PW)   { py = PH - 1; px = i - PW; }
        else { int q = i - 2 * PW; py = 1 + (q >> 1); px = (q & 1) ? (PW - 1) : 0; }
        size_t row = (size_t)img * PR + (size_t)py * PW + px;
        buf[row * 128 + threadIdx.x] = 0;     // 512 B row of zeros
    } else {
        int k = bid - 8256;                   // 960 blocks x 128 = NPIX floats
        outd[(size_t)k * 128 + threadIdx.x] = 0.f;
    }
}

// ---------------- prep: NCHW f32 -> padded NHWC bf16 ----------------
__global__ __launch_bounds__(256) void pack_features(
    const float* __restrict__ f, unsigned short* __restrict__ ft)
{
    __shared__ float tile[32][33];
    int x0 = blockIdx.x * 32;       // W/32 = 5
    int c0 = blockIdx.y * 32;       // C/32 = 8
    int by = blockIdx.z;            // B*H = 768
    int b = by / HH, y = by % HH;
    int tx = threadIdx.x & 31, tg = threadIdx.x >> 5;   // tg 0..7
    const float* src = f + (((size_t)(b * CIN + c0) * HH + y) * WW) + x0;
    #pragma unroll
    for (int i = 0; i < 4; ++i) {
        int cl = tg + i * 8;
        tile[cl][tx] = src[(size_t)cl * HH * WW + tx];
    }
    __syncthreads();
    size_t rbase = (size_t)b * PR + (size_t)(y + 1) * PW + (x0 + 1);
    #pragma unroll
    for (int i = 0; i < 4; ++i) {
        int xl = tg + i * 8;
        ft[(rbase + xl) * 256 + c0 + tx] = f2bf(tile[tx][xl]);
    }
}

// ---------------- 3x3 conv, implicit GEMM, padded input, shared-dy B staging ----------------
// r3 verified: 3 blocks/CU (launch_bounds(256,3)) -> MfmaUtil 46%, 219 us. LDS port nearing
// saturation (294KB rd + 101KB wr per CU-iter ~ 1150-1550 cyc of 1949 wall) -> a 4th block
// should recover most of the remaining stall IF regs fit 128/wave (acc 64 AGPR + <=64 VGPR).
// MINW template: conv1 runs <4> (pure A/B experiment vs r3), conv2 runs <3> (safe) —
// per-kernel rocprof rows attribute each independently (note rule #19: co-compiled
// instantiations share regalloc; deltas still valid).
// XCD swizzle: 120 spatial blocks = exactly one image per XCD -> L2 locality.
// K loop = 8 cc-chunks x 3 dy; 24 barrier pairs, 48 MFMA/wave/pair.
// Row-wrap: pixel j with x0+j>=WW lives at padded addr r0+j+2.
// Swizzle (conflict-free): lane l stages row l>>2, quarter (l&3)^((l>>3)&3).
// mode 0: conv2 + FUSED depth head: no bf16 output; per-block partial dot with w3 (passed
//         via uw2) over this block's 128 channels, one f32 atomicAdd per pixel into uout
//         (2 contributors/pixel; f32 add commutes -> deterministic). My=2.
// mode 1: merged conv1 (padded bf16 out, m0<256) + fused uncertainty head (m0==256), My=3.
template<int MINW>
__global__ __launch_bounds__(256, MINW) void conv3x3_mfma(
    const unsigned short* __restrict__ inP,
    const unsigned short* __restrict__ wT,
    const float* __restrict__ scale, const float* __restrict__ bias,
    unsigned short* __restrict__ outT,
    float* __restrict__ uout,
    const float* __restrict__ uw2, const float* __restrict__ ub2,
    int Cout, int mode, int My)
{
    __shared__ unsigned short Alds[3 * 128 * 32];   // 24576 B, [pos][slot][...]
    __shared__ unsigned short Blds[144 * 32];       // 9216 B
    __shared__ float usum[2][128];

    const int t = threadIdx.x;
    const int wave = t >> 6;
    const int l = t & 63;

    const int lid = blockIdx.x;
    const int xcd = lid & 7;
    const int j = lid >> 3;
    const int n0 = (xcd * 120 + j / My) * 128;
    const int m0 = (j % My) * 128;
    const bool is_unc = (mode == 1) && (m0 == 256);

    const int b0 = n0 / IMG;
    const int rem0 = n0 % IMG;
    const int y0 = rem0 / WW;
    const int x0 = rem0 % WW;
    const int r0 = b0 * PR + (y0 + 1) * PW + (x0 + 1);   // padded row of first output pixel

    const int lrow = l >> 2;
    const int lkq = (l & 3) ^ ((l >> 3) & 3);

    // A staging per-lane source bases (two 16-row slots per wave)
    const unsigned short* asrc0 = wT + (size_t)(m0 + wave * 32 + lrow) * 9 * 256 + lkq * 8;
    const unsigned short* asrc1 = asrc0 + (size_t)16 * 9 * 256;

    char* AldsB = (char*)Alds;
    char* BldsB = (char*)Blds;
    char* aldst = AldsB + wave * 2048;   // + dx*8192 (+1024 for second slot)

    const int wm = wave >> 1, wn = wave & 1;
    const int quad = l >> 4, lane16 = l & 15;
    const int aoff = lane16 * 64 + ((quad ^ ((lane16 >> 1) & 3)) << 4);

    // B fragment base tile-rows: pixel j -> r0 + j (+2 if wrapped); staging origin
    // rs = r0 + (dyi-1)*PW - 8; dx adds 0..2; base = j + wrap + 7
    int browbase[4];
    #pragma unroll
    for (int i = 0; i < 4; ++i) {
        int jj = wn * 64 + i * 16 + lane16;
        browbase[i] = jj + ((x0 + jj) >= WW ? 2 : 0) + 7;
    }

    f32x4 acc[4][4];
    #pragma unroll
    for (int mt = 0; mt < 4; ++mt)
        #pragma unroll
        for (int nt = 0; nt < 4; ++nt)
            acc[mt][nt] = (f32x4){0.f, 0.f, 0.f, 0.f};

    for (int cc = 0; cc < 8; ++cc) {
        const int ccoff = cc * 32;
        for (int dyi = 0; dyi < 3; ++dyi) {
            __syncthreads();
            // ---- stage A: 3 pos-tiles (pos = dyi*3 + dx), 6 instr/wave
            const unsigned short* a0 = asrc0 + (dyi * 3) * 256 + ccoff;
            const unsigned short* a1 = asrc1 + (dyi * 3) * 256 + ccoff;
            #pragma unroll
            for (int dxp = 0; dxp < 3; ++dxp) {
                gload16(a0 + dxp * 256, aldst + dxp * 8192);
                gload16(a1 + dxp * 256, aldst + dxp * 8192 + 1024);
            }
            // ---- stage B: 144 padded rows [r0 + (dyi-1)*PW - 8, +144), 9 slots
            const ptrdiff_t rs = (ptrdiff_t)r0 + (ptrdiff_t)(dyi - 1) * PW - 8;
            const unsigned short* bs = inP + (rs + lrow) * 256 + ccoff + lkq * 8
                                           + (size_t)wave * 8192;   // wave covers slots 2w,2w+1
            gload16(bs, BldsB + wave * 2048);
            gload16(bs + 4096, BldsB + wave * 2048 + 1024);
            if (wave == 3) gload16(bs + 8192, BldsB + 8192);        // slot 8
            __syncthreads();
            // ---- compute: 3 dx shifts x 16 MFMA
            #pragma unroll
            for (int dx = 0; dx < 3; ++dx) {
                bf16x8 af[4], bfr[4];
                #pragma unroll
                for (int mt = 0; mt < 4; ++mt)
                    af[mt] = *(const bf16x8*)(AldsB + dx * 8192 + ((wm * 4 + mt) << 10) + aoff);
                #pragma unroll
                for (int i = 0; i < 4; ++i) {
                    int row = browbase[i] + dx;
                    int ba = (row << 6) + ((quad ^ ((row >> 1) & 3)) << 4);
                    bfr[i] = *(const bf16x8*)(BldsB + ba);
                }
                #pragma unroll
                for (int mt = 0; mt < 4; ++mt)
                    #pragma unroll
                    for (int nt = 0; nt < 4; ++nt)
                        acc[mt][nt] = __builtin_amdgcn_mfma_f32_16x16x32_bf16(
                            af[mt], bfr[nt], acc[mt][nt], 0, 0, 0);
            }
        }
    }

    if (is_unc) {
        // fused uncertainty head: relu(acc+ub1) dot uw2 over all 128 channels -> softplus
        const float* ub = bias + 256;
        float s[4] = {0.f, 0.f, 0.f, 0.f};
        #pragma unroll
        for (int mt = 0; mt < 4; ++mt) {
            const int mg = wm * 64 + mt * 16 + quad * 4;
            const float4 bi = *(const float4*)&ub[mg];
            const float4 uw = *(const float4*)&uw2[mg];
            #pragma unroll
            for (int nt = 0; nt < 4; ++nt) {
                s[nt] += fmaxf(acc[mt][nt][0] + bi.x, 0.f) * uw.x
                       + fmaxf(acc[mt][nt][1] + bi.y, 0.f) * uw.y
                       + fmaxf(acc[mt][nt][2] + bi.z, 0.f) * uw.z
                       + fmaxf(acc[mt][nt][3] + bi.w, 0.f) * uw.w;
            }
        }
        #pragma unroll
        for (int nt = 0; nt < 4; ++nt) {
            s[nt] += __shfl_xor(s[nt], 16);
            s[nt] += __shfl_xor(s[nt], 32);
        }
        if (quad == 0) {
            #pragma unroll
            for (int nt = 0; nt < 4; ++nt)
                usum[wm][wn * 64 + nt * 16 + lane16] = s[nt];
        }
        __syncthreads();
        if (t < 128) {
            float x = usum[0][t] + usum[1][t] + ub2[0];
            uout[n0 + t] = fmaxf(x, 0.f) + log1pf(expf(-fabsf(x)));
        }
        return;
    }

    if (mode == 0) {
        // fused depth head: partial dot of relu(acc*scale+bias) with w3 (in uw2) over this
        // block's 128 channels; reduce quad via shfl, wm via LDS, one atomicAdd per pixel.
        float s[4] = {0.f, 0.f, 0.f, 0.f};
        #pragma unroll
        for (int mt = 0; mt < 4; ++mt) {
            const int mg = m0 + wm * 64 + mt * 16 + quad * 4;
            const float4 sc = *(const float4*)&scale[mg];
            const float4 bi = *(const float4*)&bias[mg];
            const float4 w  = *(const float4*)&uw2[mg];
            #pragma unroll
            for (int nt = 0; nt < 4; ++nt) {
                s[nt] += fmaxf(acc[mt][nt][0] * sc.x + bi.x, 0.f) * w.x
                       + fmaxf(acc[mt][nt][1] * sc.y + bi.y, 0.f) * w.y
                       + fmaxf(acc[mt][nt][2] * sc.z + bi.z, 0.f) * w.z
                       + fmaxf(acc[mt][nt][3] * sc.w + bi.w, 0.f) * w.w;
            }
        }
        #pragma unroll
        for (int nt = 0; nt < 4; ++nt) {
            s[nt] += __shfl_xor(s[nt], 16);
            s[nt] += __shfl_xor(s[nt], 32);
        }
        if (quad == 0) {
            #pragma unroll
            for (int nt = 0; nt < 4; ++nt)
                usum[wm][wn * 64 + nt * 16 + lane16] = s[nt];
        }
        __syncthreads();
        if (t < 128) atomicAdd(&uout[n0 + t], usum[0][t] + usum[1][t]);
        return;
    }

    // mode 1 conv output: y = relu(acc*scale + bias) -> bf16 padded rows
    size_t obase[4];
    #pragma unroll
    for (int nt = 0; nt < 4; ++nt) {
        int n = n0 + wn * 64 + nt * 16 + lane16;
        int b = n / IMG, rem = n % IMG, yy = rem / WW, xx = rem % WW;
        obase[nt] = ((size_t)(b * PH + yy + 1) * PW + (xx + 1)) * 256;
    }
    #pragma unroll
    for (int mt = 0; mt < 4; ++mt) {
        const int mg = m0 + wm * 64 + mt * 16 + quad * 4;
        const float4 sc = *(const float4*)&scale[mg];
        const float4 bi = *(const float4*)&bias[mg];
        #pragma unroll
        for (int nt = 0; nt < 4; ++nt) {
            ushort4 pk;
            pk.x = f2bf(fmaxf(acc[mt][nt][0] * sc.x + bi.x, 0.f));
            pk.y = f2bf(fmaxf(acc[mt][nt][1] * sc.y + bi.y, 0.f));
            pk.z = f2bf(fmaxf(acc[mt][nt][2] * sc.z + bi.z, 0.f));
            pk.w = f2bf(fmaxf(acc[mt][nt][3] * sc.w + bi.w, 0.f));
            *(ushort4*)&outT[obase[nt] + mg] = pk;
        }
    }
}

// ---------------- finalize depth: x -> 1/(0.01 + 9.99*sigmoid(x + b3)) in-place ----------------
__global__ __launch_bounds__(256) void depth_transform(
    float* __restrict__ out, const float* __restrict__ b3)
{
    int i = blockIdx.x * 256 + threadIdx.x;    // 480 * 256 = NPIX exactly
    float x = out[i] + b3[0];
    float sig = 1.f / (1.f + expf(-x));
    out[i] = 1.f / (0.01f + 9.99f * sig);
}

// ---------------- per-box lower-median via 4-pass radix select on float bits ----------------
__global__ __launch_bounds__(256) void median_kernel(
    const float* __restrict__ depth, const int* __restrict__ bboxes, float* __restrict__ obj)
{
    const int bi = blockIdx.x;          // b*64 + box
    const int b = bi >> 6;
    const int* bb = bboxes + (size_t)bi * 4;
    int x1 = max(bb[0], 0), y1 = max(bb[1], 0);
    int x2 = min(bb[2], WW), y2 = min(bb[3], HH);
    int w = x2 - x1, h = y2 - y1;
    if (w <= 0 || h <= 0) {
        if (threadIdx.x == 0) obj[bi] = 0.f;
        return;
    }
    const int wh = w * h;
    int tgt = (wh - 1) >> 1;            // lower median index
    const float* dbase = depth + (size_t)b * HH * WW;

    __shared__ unsigned int hist[256];
    __shared__ unsigned int sel_prefix, sel_target;
    unsigned int prefix = 0;

    for (int pass = 0; pass < 4; ++pass) {
        const int shift = 24 - 8 * pass;
        hist[threadIdx.x] = 0;
        __syncthreads();
        const unsigned int mask_high = (pass == 0) ? 0u : (0xFFFFFFFFu << (shift + 8));
        for (int idx = threadIdx.x; idx < wh; idx += 256) {
            int yy = y1 + idx / w, xx = x1 + idx % w;
            unsigned int uu = __float_as_uint(dbase[yy * WW + xx]);
            if ((uu & mask_high) == (prefix & mask_high))
                atomicAdd(&hist[(uu >> shift) & 255], 1u);
        }
        __syncthreads();
        if (threadIdx.x == 0) {
            unsigned int cum = 0;
            for (int bin = 0; bin < 256; ++bin) {
                unsigned int c = hist[bin];
                if (cum + c > (unsigned int)tgt) {
                    sel_target = (unsigned int)tgt - cum;
                    sel_prefix = prefix | ((unsigned int)bin << shift);
                    break;
                }
                cum += c;
            }
        }
        __syncthreads();
        prefix = sel_prefix;
        tgt = (int)sel_target;
    }
    if (threadIdx.x == 0) obj[bi] = __uint_as_float(prefix);
}

extern "C" void kernel_launch(void* const* d_in, const int* in_sizes, int n_in,
                              void* d_out, int out_size, void* d_ws, size_t ws_size,
                              hipStream_t stream) {
    const float* features = (const float*)d_in[0];
    const int*   bboxes   = (const int*)d_in[1];
    const float* w1  = (const float*)d_in[2];
    const float* b1  = (const float*)d_in[3];
    const float* g1  = (const float*)d_in[4];
    const float* be1 = (const float*)d_in[5];
    const float* m1  = (const float*)d_in[6];
    const float* v1  = (const float*)d_in[7];
    const float* w2  = (const float*)d_in[8];
    const float* b2  = (const float*)d_in[9];
    const float* g2  = (const float*)d_in[10];
    const float* be2 = (const float*)d_in[11];
    const float* m2  = (const float*)d_in[12];
    const float* v2  = (const float*)d_in[13];
    const float* w3  = (const float*)d_in[14];
    const float* b3  = (const float*)d_in[15];
    const float* uw1 = (const float*)d_in[16];
    const float* ub1 = (const float*)d_in[17];
    const float* uw2 = (const float*)d_in[18];
    const float* ub2 = (const float*)d_in[19];
    float* out = (float*)d_out;

    char* ws = (char*)d_ws;
    // layout (bytes). Padded buffers have 8 KB read-slack gaps on both sides.
    unsigned short* featP = (unsigned short*)(ws + 8192);        // 65,028,096 -> end 65,036,288
    unsigned short* h1P   = (unsigned short*)(ws + 65044480);    // end 130,072,576
    unsigned short* w1T   = (unsigned short*)(ws + 130080768);   // 256 rows, 1,179,648 B
    unsigned short* uw1T  = w1T + 256 * 2304;                    // 128 rows right after -> combined 384
    unsigned short* w2T   = uw1T + 128 * 2304;                   // 1,179,648 B
    float* scale1 = (float*)(w2T + 589824);                      // 384
    float* bias1  = scale1 + 384;                                // 384 (256 BN-fold + 128 ub1)
    float* scale2 = bias1 + 384;                                 // 256
    float* bias2  = scale2 + 256;                                // 256

    prep_scalars<<<1, 256, 0, stream>>>(b1, g1, be1, m1, v1, b2, g2, be2, m2, v2, ub1,
                                        scale1, bias1, scale2, bias2);
    prep_weights<<<5760, 256, 0, stream>>>(w1, w2, uw1, w1T, w2T, uw1T);
    // pads + zero depth-accumulator region (out[0..NPIX))
    zero_pads<<<9216, 128, 0, stream>>>((unsigned int*)featP, (unsigned int*)h1P, out);
    pack_features<<<dim3(WW / 32, CIN / 32, BATCH * HH), 256, 0, stream>>>(features, featP);

    // merged conv1 (BN+ReLU, padded out) + fused uncertainty head; My=3, 2880 blocks.
    // <4>: the occupancy-squeeze experiment (r3 A/B).
    conv3x3_mfma<4><<<2880, 256, 0, stream>>>(
        featP, w1T, scale1, bias1, h1P, out + NPIX, uw2, ub2, 256, 1, 3);
    // conv2 + fused depth head: atomicAdd partial dots into out[0..NPIX); My=2, 1920 blocks.
    // <3>: safe occupancy; w3 rides in the uw2 slot.
    conv3x3_mfma<3><<<1920, 256, 0, stream>>>(
        h1P, w2T, scale2, bias2, nullptr, out, w3, nullptr, 256, 0, 2);

    depth_transform<<<NPIX / 256, 256, 0, stream>>>(out, b3);
    median_kernel<<<BATCH * 64, 256, 0, stream>>>(out, bboxes, out + 2 * NPIX);
}